// Round 1
// 571.666 us; speedup vs baseline: 1.0063x; 1.0063x over previous
//
#include <hip/hip_runtime.h>
#include <cstdint>
#include <cstddef>

#define NNODES 50000
#define NEDGES 800000
#define NGR    64
#define INDIM  128
#define HIDD   64

typedef __attribute__((ext_vector_type(8))) short bf16x8;
typedef __attribute__((ext_vector_type(4))) float f32x4;

__device__ __forceinline__ float lrelu(float x) { return x > 0.f ? x : 0.2f * x; }
__device__ __forceinline__ float eluf(float x)  { return x > 0.f ? x : expm1f(x); }
__device__ __forceinline__ float bf2f(unsigned short u) {
    return __uint_as_float((unsigned int)u << 16);
}
__device__ __forceinline__ unsigned short f2bf(float x) {   // RNE
    unsigned int u = __float_as_uint(x);
    return (unsigned short)((u + 0x7fffu + ((u >> 16) & 1u)) >> 16);
}
__device__ __forceinline__ float lo16(unsigned int u) { return __uint_as_float(u << 16); }
__device__ __forceinline__ float hi16(unsigned int u) { return __uint_as_float(u & 0xffff0000u); }

// ---------------------------------------------------------------------------
// fp32 -> bf16 (weight matrices only)
// ---------------------------------------------------------------------------
__global__ void cvt_f2b(const float* __restrict__ in, unsigned short* __restrict__ out, int n4) {
    int i = blockIdx.x * 256 + threadIdx.x;
    if (i < n4) {
        float4 v = ((const float4*)in)[i];
        ushort4 o;
        o.x = f2bf(v.x); o.y = f2bf(v.y); o.z = f2bf(v.z); o.w = f2bf(v.w);
        ((ushort4*)out)[i] = o;
    }
}

// ---------------------------------------------------------------------------
// CSR build (both graphs batched via blockIdx.y). int64 inputs arrive int32.
// ---------------------------------------------------------------------------
__global__ void count_dst(const int* __restrict__ ei0, const int* __restrict__ ei1,
                          int* __restrict__ cnt, int E, int N) {
    const int* ei = blockIdx.y ? ei1 : ei0;
    int* c = cnt + blockIdx.y * N;
    int e = blockIdx.x * 256 + threadIdx.x;
    if (e < E) atomicAdd(&c[ei[E + e]], 1);
}

__global__ __launch_bounds__(256) void scan_part(const int* __restrict__ cnt,
                                                 int* __restrict__ psum, int n) {
    __shared__ int ws[4];
    const int* c = cnt + blockIdx.y * n;
    int* p = psum + blockIdx.y * 256;
    int lane = threadIdx.x & 63, w = threadIdx.x >> 6;
    int i = blockIdx.x * 256 + threadIdx.x;
    int v = (i < n) ? c[i] : 0;
    #pragma unroll
    for (int off = 32; off >= 1; off >>= 1) v += __shfl_xor(v, off, 64);
    if (lane == 0) ws[w] = v;
    __syncthreads();
    if (threadIdx.x == 0) p[blockIdx.x] = ws[0] + ws[1] + ws[2] + ws[3];
}

__global__ __launch_bounds__(256) void scan_tops(int* __restrict__ psum,
                                                 int* __restrict__ rp, int nb, int n) {
    __shared__ int wsum[4];
    int* p = psum + blockIdx.x * 256;
    int* r = rp + blockIdx.x * (n + 1);
    int tid = threadIdx.x, lane = tid & 63, w = tid >> 6;
    int v = (tid < nb) ? p[tid] : 0;
    int x = v;
    #pragma unroll
    for (int off = 1; off < 64; off <<= 1) {
        int t = __shfl_up(x, off, 64);
        if (lane >= off) x += t;
    }
    if (lane == 63) wsum[w] = x;
    __syncthreads();
    int add = 0;
    for (int k = 0; k < w; k++) add += wsum[k];
    int incl = x + add;
    if (tid < nb) p[tid] = incl - v;
    if (tid == nb - 1) r[n] = incl;
}

__global__ __launch_bounds__(256) void scan_fin(const int* __restrict__ cnt,
                                                const int* __restrict__ psum,
                                                int* __restrict__ rp, int n) {
    __shared__ int wsum[4];
    const int* c = cnt + blockIdx.y * n;
    const int* p = psum + blockIdx.y * 256;
    int* r = rp + blockIdx.y * (n + 1);
    int tid = threadIdx.x, lane = tid & 63, w = tid >> 6;
    int i = blockIdx.x * 256 + tid;
    int v = (i < n) ? c[i] : 0;
    int x = v;
    #pragma unroll
    for (int off = 1; off < 64; off <<= 1) {
        int t = __shfl_up(x, off, 64);
        if (lane >= off) x += t;
    }
    if (lane == 63) wsum[w] = x;
    __syncthreads();
    int add = p[blockIdx.x];
    for (int k = 0; k < w; k++) add += wsum[k];
    if (i < n) r[i] = x + add - v;
}

__global__ void fill_csr(const int* __restrict__ ei0, const int* __restrict__ ei1,
                         const int* __restrict__ rp, int* __restrict__ fc,
                         int* __restrict__ col, int E, int N) {
    int g = blockIdx.y;
    const int* ei = g ? ei1 : ei0;
    const int* r = rp + g * (N + 1);
    int* f = fc + g * N;
    int* cl = col + (size_t)g * E;
    int e = blockIdx.x * 256 + threadIdx.x;
    if (e < E) {
        int s = ei[e];
        int d = ei[E + e];
        int pos = atomicAdd(&f[d], 1);
        cl[r[d] + pos] = s;
    }
}

// ---------------------------------------------------------------------------
// MFMA bf16 GEMM with fused alpha epilogue (round 7/9 verified).
// ---------------------------------------------------------------------------
template<int BN, int WM, int WN, bool AF32>
__global__ __launch_bounds__(256) void gemm_mfma(const void* __restrict__ A0,
                                                 const void* __restrict__ A1,
                                                 size_t Ags,
                                                 const unsigned short* __restrict__ Bw,
                                                 unsigned short* __restrict__ C,
                                                 size_t Cgs,
                                                 int M, int K, int N,
                                                 const float* __restrict__ a_src,
                                                 const float* __restrict__ a_dst,
                                                 float* __restrict__ as_o,
                                                 float* __restrict__ ad_o,
                                                 int hstride, int ags) {
    constexpr int BM = 128, BK = 64;
    constexpr int MI = WM / 16, NI = WN / 16;
    constexpr int LDA = BK + 8;
    __shared__ unsigned short Asm[BM * LDA];
    __shared__ unsigned short Bsm[BN * LDA];
    int gph = blockIdx.z;
    const float* Af = (const float*)(gph ? A1 : A0);
    const unsigned short* Ab = (const unsigned short*)A0 + (size_t)gph * Ags;
    unsigned short* Cg = C + (size_t)gph * Cgs;
    float* aso = as_o + (size_t)gph * ags;
    float* ado = ad_o + (size_t)gph * ags;
    int tid = threadIdx.x;
    int lane = tid & 63, wave = tid >> 6;
    int l15 = lane & 15, quad = lane >> 4;
    int wm0, wn0;
    if (BN == 128) { wm0 = (wave >> 1) * 64; wn0 = (wave & 1) * 64; }
    else           { wm0 = wave * 32;        wn0 = 0; }
    int row0 = blockIdx.x * BM;
    int c0 = blockIdx.y * BN;

    f32x4 acc[MI][NI];
    #pragma unroll
    for (int mi = 0; mi < MI; mi++)
        #pragma unroll
        for (int ni = 0; ni < NI; ni++)
            acc[mi][ni] = (f32x4){0.f, 0.f, 0.f, 0.f};

    for (int k0 = 0; k0 < K; k0 += BK) {
        #pragma unroll
        for (int q = 0; q < BM / 32; q++) {
            int idx = q * 256 + tid;
            int r = idx >> 3, kc = idx & 7;
            int row = row0 + r;
            if (AF32) {
                float4 v0 = make_float4(0.f, 0.f, 0.f, 0.f), v1 = v0;
                if (row < M) {
                    v0 = *(const float4*)(Af + (size_t)row * K + k0 + kc * 8);
                    v1 = *(const float4*)(Af + (size_t)row * K + k0 + kc * 8 + 4);
                }
                unsigned short t[8] = {f2bf(v0.x), f2bf(v0.y), f2bf(v0.z), f2bf(v0.w),
                                       f2bf(v1.x), f2bf(v1.y), f2bf(v1.z), f2bf(v1.w)};
                *(uint4*)&Asm[r * LDA + kc * 8] = *(uint4*)t;
            } else {
                uint4 v = make_uint4(0u, 0u, 0u, 0u);
                if (row < M) v = *(const uint4*)(Ab + (size_t)row * K + k0 + kc * 8);
                *(uint4*)&Asm[r * LDA + kc * 8] = v;
            }
        }
        #pragma unroll
        for (int q = 0; q < BN / 32; q++) {
            int idx = q * 256 + tid;
            int n  = idx & (BN - 1);
            int kc = idx / BN;
            unsigned short tmp[8];
            #pragma unroll
            for (int j = 0; j < 8; j++)
                tmp[j] = Bw[(size_t)(k0 + kc * 8 + j) * N + c0 + n];
            *(uint4*)&Bsm[n * LDA + kc * 8] = *(uint4*)tmp;
        }
        __syncthreads();
        #pragma unroll
        for (int kb = 0; kb < 2; kb++) {
            bf16x8 af[MI], bfr[NI];
            #pragma unroll
            for (int mi = 0; mi < MI; mi++)
                af[mi] = *(bf16x8*)&Asm[(wm0 + mi * 16 + l15) * LDA + kb * 32 + quad * 8];
            #pragma unroll
            for (int ni = 0; ni < NI; ni++)
                bfr[ni] = *(bf16x8*)&Bsm[(wn0 + ni * 16 + l15) * LDA + kb * 32 + quad * 8];
            #pragma unroll
            for (int mi = 0; mi < MI; mi++)
                #pragma unroll
                for (int ni = 0; ni < NI; ni++)
                    acc[mi][ni] = __builtin_amdgcn_mfma_f32_16x16x32_bf16(
                        af[mi], bfr[ni], acc[mi][ni], 0, 0, 0);
        }
        __syncthreads();
    }
    #pragma unroll
    for (int mi = 0; mi < MI; mi++) {
        #pragma unroll
        for (int r = 0; r < 4; r++) {
            int row = row0 + wm0 + mi * 16 + quad * 4 + r;
            if (row < M) {
                #pragma unroll
                for (int ni = 0; ni < NI; ni++) {
                    int colg = c0 + wn0 + ni * 16 + l15;
                    Cg[(size_t)row * N + colg] = f2bf(acc[mi][ni][r]);
                }
            }
        }
    }
    int headc = (c0 + wn0) >> 6;
    float a_s[NI], a_d[NI];
    #pragma unroll
    for (int ni = 0; ni < NI; ni++) {
        a_s[ni] = a_src[headc * 64 + ni * 16 + l15];
        a_d[ni] = a_dst[headc * 64 + ni * 16 + l15];
    }
    #pragma unroll
    for (int mi = 0; mi < MI; mi++) {
        #pragma unroll
        for (int r = 0; r < 4; r++) {
            float ps = 0.f, pd = 0.f;
            #pragma unroll
            for (int ni = 0; ni < NI; ni++) {
                ps += acc[mi][ni][r] * a_s[ni];
                pd += acc[mi][ni][r] * a_d[ni];
            }
            #pragma unroll
            for (int off = 1; off < 16; off <<= 1) {
                ps += __shfl_xor(ps, off, 64);
                pd += __shfl_xor(pd, off, 64);
            }
            int row = row0 + wm0 + mi * 16 + quad * 4 + r;
            if (l15 == 0 && row < M) {
                aso[row * hstride + headc] = ps;
                ado[row * hstride + headc] = pd;
            }
        }
    }
}

// ---------------------------------------------------------------------------
// GAT aggregation, 4 heads x 64 dim, one wave per dst node.
// v2: 4 edges in flight (lane = 16*p + c, c covers uint4 pair {2c,2c+1} ->
// channels [16c,16c+16), headc = c>>2), software-pipelined one quad deep
// (next quad's row loads issued before current quad's FMAs), and the next
// j-block's colv/as gather prefetched under the current block's edge work.
// Weight(edge e, head h) held by loader lane (h<<4)|e; shfl(wl,(headc<<4)|ec).
// ---------------------------------------------------------------------------
__global__ __launch_bounds__(256) void agg_h4(const unsigned short* __restrict__ h,
                                              size_t hgs,
                                              const float* __restrict__ as_,
                                              const float* __restrict__ ad_, int ags,
                                              const int* __restrict__ rp,
                                              const int* __restrict__ col,
                                              const float* __restrict__ bias,
                                              unsigned short* __restrict__ out,
                                              size_t ogs, int n, int E) {
    int gph = blockIdx.y;
    const uint4* h4 = (const uint4*)(h + (size_t)gph * hgs);   // 32 uint4 per row
    const float* as = as_ + (size_t)gph * ags;
    const float* adp = ad_ + (size_t)gph * ags;
    const int* r = rp + gph * (n + 1);
    const int* cl = col + (size_t)gph * E;
    unsigned short* og = out + (size_t)gph * ogs;

    int wave = threadIdx.x >> 6, lane = threadIdx.x & 63;
    int node = blockIdx.x * 4 + wave;
    if (node >= n) return;
    int p = lane >> 4;            // edge slot within quad (0..3); == loader quad
    int c = lane & 15;            // uint4-pair index -> channels [16c,16c+16)
    int headc = c >> 2;           // this lane's channel head
    float adv_q = adp[node * 4 + p];         // loader's head adv
    // self loop (counted once, on p==0 group)
    float w0 = __expf(lrelu(as[node * 4 + headc] + adp[node * 4 + headc]));
    float m0 = (p == 0) ? w0 : 0.f;
    uint4 hu0 = h4[(size_t)node * 32 + 2 * c];
    uint4 hu1 = h4[(size_t)node * 32 + 2 * c + 1];
    float den = m0;
    float a0  = lo16(hu0.x) * m0, a1  = hi16(hu0.x) * m0;
    float a2  = lo16(hu0.y) * m0, a3  = hi16(hu0.y) * m0;
    float a4  = lo16(hu0.z) * m0, a5  = hi16(hu0.z) * m0;
    float a6  = lo16(hu0.w) * m0, a7  = hi16(hu0.w) * m0;
    float a8  = lo16(hu1.x) * m0, a9  = hi16(hu1.x) * m0;
    float a10 = lo16(hu1.y) * m0, a11 = hi16(hu1.y) * m0;
    float a12 = lo16(hu1.z) * m0, a13 = hi16(hu1.z) * m0;
    float a14 = lo16(hu1.w) * m0, a15 = hi16(hu1.w) * m0;
    int beg = __builtin_amdgcn_readfirstlane(r[node]);
    int end = __builtin_amdgcn_readfirstlane(r[node + 1]);
    int hbase = headc << 4;
    int j = beg;
    int m = end - j; if (m > 16) m = 16;
    int colv = 0; float asv = 0.f;
    if (j < end) {
        colv = cl[j + (c < m ? c : m - 1)];
        asv = as[colv * 4 + p];
    }
    while (j < end) {
        int jn = j + 16;
        int mn = end - jn; if (mn > 16) mn = 16;
        int colv_n = 0; float asv_n = 0.f;
        if (mn > 0) {            // prefetch next block's weight inputs early
            colv_n = cl[jn + (c < mn ? c : mn - 1)];
            asv_n = as[colv_n * 4 + p];
        }
        float wl = __expf(lrelu(asv + adv_q));   // weight(edge c, head p)
        // pipelined quads: next quad's loads in flight during current FMAs
        int e0 = p;
        int ec = e0 < m ? e0 : m - 1;
        float we = __shfl(wl, hbase | ec);
        if (e0 >= m) we = 0.f;
        int s = __shfl(colv, ec);
        uint4 u0 = h4[(size_t)s * 32 + 2 * c];
        uint4 u1 = h4[(size_t)s * 32 + 2 * c + 1];
        for (int base = 4; base < m; base += 4) {
            int e2 = base + p;
            int ec2 = e2 < m ? e2 : m - 1;
            float we2 = __shfl(wl, hbase | ec2);
            if (e2 >= m) we2 = 0.f;
            int s2 = __shfl(colv, ec2);
            uint4 v0 = h4[(size_t)s2 * 32 + 2 * c];
            uint4 v1 = h4[(size_t)s2 * 32 + 2 * c + 1];
            den += we;
            a0  += lo16(u0.x) * we; a1  += hi16(u0.x) * we;
            a2  += lo16(u0.y) * we; a3  += hi16(u0.y) * we;
            a4  += lo16(u0.z) * we; a5  += hi16(u0.z) * we;
            a6  += lo16(u0.w) * we; a7  += hi16(u0.w) * we;
            a8  += lo16(u1.x) * we; a9  += hi16(u1.x) * we;
            a10 += lo16(u1.y) * we; a11 += hi16(u1.y) * we;
            a12 += lo16(u1.z) * we; a13 += hi16(u1.z) * we;
            a14 += lo16(u1.w) * we; a15 += hi16(u1.w) * we;
            we = we2; u0 = v0; u1 = v1;
        }
        den += we;
        a0  += lo16(u0.x) * we; a1  += hi16(u0.x) * we;
        a2  += lo16(u0.y) * we; a3  += hi16(u0.y) * we;
        a4  += lo16(u0.z) * we; a5  += hi16(u0.z) * we;
        a6  += lo16(u0.w) * we; a7  += hi16(u0.w) * we;
        a8  += lo16(u1.x) * we; a9  += hi16(u1.x) * we;
        a10 += lo16(u1.y) * we; a11 += hi16(u1.y) * we;
        a12 += lo16(u1.z) * we; a13 += hi16(u1.z) * we;
        a14 += lo16(u1.w) * we; a15 += hi16(u1.w) * we;
        j = jn; m = mn; colv = colv_n; asv = asv_n;
    }
    // combine the four edge-slot groups (lane^16, lane^32 have same channels)
    #pragma unroll
    for (int off = 16; off < 64; off <<= 1) {
        den += __shfl_xor(den, off);
        a0  += __shfl_xor(a0,  off); a1  += __shfl_xor(a1,  off);
        a2  += __shfl_xor(a2,  off); a3  += __shfl_xor(a3,  off);
        a4  += __shfl_xor(a4,  off); a5  += __shfl_xor(a5,  off);
        a6  += __shfl_xor(a6,  off); a7  += __shfl_xor(a7,  off);
        a8  += __shfl_xor(a8,  off); a9  += __shfl_xor(a9,  off);
        a10 += __shfl_xor(a10, off); a11 += __shfl_xor(a11, off);
        a12 += __shfl_xor(a12, off); a13 += __shfl_xor(a13, off);
        a14 += __shfl_xor(a14, off); a15 += __shfl_xor(a15, off);
    }
    if (p == 0) {   // lanes 0..15, each writes channels [16c,16c+16)
        float rden = 1.f / (den + 1e-16f);
        const float4* b4 = (const float4*)bias;
        float4 b0 = b4[c * 4], b1 = b4[c * 4 + 1];
        float4 b2 = b4[c * 4 + 2], b3 = b4[c * 4 + 3];
        unsigned short t[16];
        t[0]  = f2bf(eluf(a0  * rden + b0.x)); t[1]  = f2bf(eluf(a1  * rden + b0.y));
        t[2]  = f2bf(eluf(a2  * rden + b0.z)); t[3]  = f2bf(eluf(a3  * rden + b0.w));
        t[4]  = f2bf(eluf(a4  * rden + b1.x)); t[5]  = f2bf(eluf(a5  * rden + b1.y));
        t[6]  = f2bf(eluf(a6  * rden + b1.z)); t[7]  = f2bf(eluf(a7  * rden + b1.w));
        t[8]  = f2bf(eluf(a8  * rden + b2.x)); t[9]  = f2bf(eluf(a9  * rden + b2.y));
        t[10] = f2bf(eluf(a10 * rden + b2.z)); t[11] = f2bf(eluf(a11 * rden + b2.w));
        t[12] = f2bf(eluf(a12 * rden + b3.x)); t[13] = f2bf(eluf(a13 * rden + b3.y));
        t[14] = f2bf(eluf(a14 * rden + b3.z)); t[15] = f2bf(eluf(a15 * rden + b3.w));
        uint4* orow = (uint4*)(og + (size_t)node * 256);
        orow[2 * c]     = *(uint4*)&t[0];
        orow[2 * c + 1] = *(uint4*)&t[8];
    }
}

// ---------------------------------------------------------------------------
// conv2 aggregation: 1 head x 64 dim, one wave per dst node.
// 8 edges in flight: lane = 8*p + c; 8 lanes cover the 128B row (uint4).
// v2: inner loop software-pipelined one octet deep; next 64-edge block's
// colv/as gather prefetched under the current block's edge work.
// ---------------------------------------------------------------------------
__global__ __launch_bounds__(256) void agg_h1(const unsigned short* __restrict__ h,
                                              size_t hgs,
                                              const float* __restrict__ as_,
                                              const float* __restrict__ ad_,
                                              const int* __restrict__ rp,
                                              const int* __restrict__ col,
                                              const float* __restrict__ bias,
                                              float* __restrict__ out,
                                              size_t ogs, int n, int E) {
    int gph = blockIdx.y;
    const uint4* h4 = (const uint4*)(h + (size_t)gph * hgs);   // 8 uint4 per row
    const float* as = as_ + (size_t)gph * n;
    const float* adp = ad_ + (size_t)gph * n;
    const int* r = rp + gph * (n + 1);
    const int* cl = col + (size_t)gph * E;
    float* og = out + (size_t)gph * ogs;

    int wave = threadIdx.x >> 6, lane = threadIdx.x & 63;
    int node = blockIdx.x * 4 + wave;
    if (node >= n) return;
    int p = lane >> 3;            // edge slot within octet
    int c = lane & 7;             // uint4 index in row -> channels [8c,8c+8)
    float adv = adp[node];
    float w0 = __expf(lrelu(as[node] + adv));
    float m0 = (p == 0) ? w0 : 0.f;
    uint4 hu = h4[(size_t)node * 8 + c];
    float den = m0;
    float a0 = lo16(hu.x) * m0, a1 = hi16(hu.x) * m0;
    float a2 = lo16(hu.y) * m0, a3 = hi16(hu.y) * m0;
    float a4 = lo16(hu.z) * m0, a5 = hi16(hu.z) * m0;
    float a6 = lo16(hu.w) * m0, a7 = hi16(hu.w) * m0;
    int beg = __builtin_amdgcn_readfirstlane(r[node]);
    int end = __builtin_amdgcn_readfirstlane(r[node + 1]);
    int j = beg;
    int m = end - j; if (m > 64) m = 64;
    int colv = 0; float asv = 0.f;
    if (j < end) {
        colv = cl[j + (lane < m ? lane : m - 1)];
        asv = as[colv];
    }
    while (j < end) {
        int jn = j + 64;
        int mn = end - jn; if (mn > 64) mn = 64;
        int colv_n = 0; float asv_n = 0.f;
        if (mn > 0) {            // prefetch next block's weight inputs early
            colv_n = cl[jn + (lane < mn ? lane : mn - 1)];
            asv_n = as[colv_n];
        }
        float wl = __expf(lrelu(asv + adv));
        // pipelined octets
        int e0 = p;
        int ec = e0 < m ? e0 : m - 1;
        float we = __shfl(wl, ec);
        if (e0 >= m) we = 0.f;
        int s = __shfl(colv, ec);
        uint4 u = h4[(size_t)s * 8 + c];
        for (int base = 8; base < m; base += 8) {
            int e2 = base + p;
            int ec2 = e2 < m ? e2 : m - 1;
            float we2 = __shfl(wl, ec2);
            if (e2 >= m) we2 = 0.f;
            int s2 = __shfl(colv, ec2);
            uint4 u2 = h4[(size_t)s2 * 8 + c];
            den += we;
            a0 += lo16(u.x) * we; a1 += hi16(u.x) * we;
            a2 += lo16(u.y) * we; a3 += hi16(u.y) * we;
            a4 += lo16(u.z) * we; a5 += hi16(u.z) * we;
            a6 += lo16(u.w) * we; a7 += hi16(u.w) * we;
            we = we2; u = u2;
        }
        den += we;
        a0 += lo16(u.x) * we; a1 += hi16(u.x) * we;
        a2 += lo16(u.y) * we; a3 += hi16(u.y) * we;
        a4 += lo16(u.z) * we; a5 += hi16(u.z) * we;
        a6 += lo16(u.w) * we; a7 += hi16(u.w) * we;
        j = jn; m = mn; colv = colv_n; asv = asv_n;
    }
    #pragma unroll
    for (int off = 8; off < 64; off <<= 1) {
        den += __shfl_xor(den, off);
        a0 += __shfl_xor(a0, off); a1 += __shfl_xor(a1, off);
        a2 += __shfl_xor(a2, off); a3 += __shfl_xor(a3, off);
        a4 += __shfl_xor(a4, off); a5 += __shfl_xor(a5, off);
        a6 += __shfl_xor(a6, off); a7 += __shfl_xor(a7, off);
    }
    if (p == 0) {
        float rden = 1.f / (den + 1e-16f);
        float4 b0 = ((const float4*)bias)[c * 2];
        float4 b1 = ((const float4*)bias)[c * 2 + 1];
        float4 o0, o1;
        o0.x = eluf(a0 * rden + b0.x); o0.y = eluf(a1 * rden + b0.y);
        o0.z = eluf(a2 * rden + b0.z); o0.w = eluf(a3 * rden + b0.w);
        o1.x = eluf(a4 * rden + b1.x); o1.y = eluf(a5 * rden + b1.y);
        o1.z = eluf(a6 * rden + b1.z); o1.w = eluf(a7 * rden + b1.w);
        float* orow = og + (size_t)node * 64 + c * 8;
        *(float4*)orow = o0;
        *(float4*)(orow + 4) = o1;
    }
}

// ---------------------------------------------------------------------------
// Mean pool over SORTED batch ids
// ---------------------------------------------------------------------------
__device__ __forceinline__ int lbound(const int* __restrict__ a, int n, int key) {
    int lo = 0, hi = n;
    while (lo < hi) {
        int mid = (lo + hi) >> 1;
        if (a[mid] < key) lo = mid + 1; else hi = mid;
    }
    return lo;
}

__global__ __launch_bounds__(256) void pool_mean(const float* __restrict__ g2,
                                                 size_t ggs,
                                                 const int* __restrict__ b0,
                                                 const int* __restrict__ b1,
                                                 float* __restrict__ out, int n) {
    __shared__ float red[4][64];
    __shared__ int bnds[2];
    int gph = blockIdx.y;
    const int* batch = gph ? b1 : b0;
    const float* gg = g2 + (size_t)gph * ggs;
    float* og = out + (size_t)gph * NGR * HIDD;
    int g = blockIdx.x;
    if (threadIdx.x < 2) bnds[threadIdx.x] = lbound(batch, n, g + (int)threadIdx.x);
    __syncthreads();
    int s = bnds[0], e = bnds[1];
    int lane = threadIdx.x & 63, wave = threadIdx.x >> 6;
    float acc = 0.f;
    for (int i = s + wave; i < e; i += 4)
        acc += gg[(size_t)i * 64 + lane];
    red[wave][lane] = acc;
    __syncthreads();
    if (wave == 0) {
        float sum = red[0][lane] + red[1][lane] + red[2][lane] + red[3][lane];
        og[g * 64 + lane] = sum / fmaxf((float)(e - s), 1.0f);
    }
}

// ---------------------------------------------------------------------------
extern "C" void kernel_launch(void* const* d_in, const int* in_sizes, int n_in,
                              void* d_out, int out_size, void* d_ws, size_t ws_size,
                              hipStream_t stream) {
    const int N = NNODES, E = NEDGES;

    const float* x1 = (const float*)d_in[0];
    const float* x2 = (const float*)d_in[3];
    const int* ei1v = (const int*)d_in[1];
    const int* ei2v = (const int*)d_in[4];
    const int* ba1  = (const int*)d_in[2];
    const int* ba2  = (const int*)d_in[5];
    const float* W1     = (const float*)d_in[6];
    const float* a_src1 = (const float*)d_in[7];
    const float* a_dst1 = (const float*)d_in[8];
    const float* b1     = (const float*)d_in[9];
    const float* W2     = (const float*)d_in[10];
    const float* a_src2 = (const float*)d_in[11];
    const float* a_dst2 = (const float*)d_in[12];
    const float* b2     = (const float*)d_in[13];

    // Workspace (~125 MB):
    //  R1: h1 bf16 (51.2M) -> g2 fp32 (25.6M)
    //  R2: g1 bf16 (51.2M)
    //  R3: h2 bf16 (12.8M)
    char* ws = (char*)d_ws;
    size_t off = 0;
    auto carve = [&](size_t bytes) -> char* {
        char* p = ws + off;
        off = (off + bytes + 255) & ~(size_t)255;
        return p;
    };
    char* R1 = carve((size_t)2 * N * 256 * 2);
    char* R2 = carve((size_t)2 * N * 256 * 2);
    char* R3 = carve((size_t)2 * N * 64 * 2);
    int*   col  = (int*)carve((size_t)2 * E * 4);
    int*   rp   = (int*)carve((size_t)2 * (N + 1) * 4);
    int*   cntN = (int*)carve((size_t)2 * N * 4);
    int*   psum = (int*)carve(2 * 256 * 4);
    float* as1  = (float*)carve((size_t)2 * N * 4 * 4);
    float* ad1  = (float*)carve((size_t)2 * N * 4 * 4);
    float* as2  = (float*)carve((size_t)2 * N * 4);
    float* ad2  = (float*)carve((size_t)2 * N * 4);
    unsigned short* W1b = (unsigned short*)carve(INDIM * 256 * 2);
    unsigned short* W2b = (unsigned short*)carve(256 * HIDD * 2);

    unsigned short* h1 = (unsigned short*)R1;            // [2][N*256] bf16
    unsigned short* g1 = (unsigned short*)R2;            // [2][N*256] bf16
    unsigned short* h2 = (unsigned short*)R3;            // [2][N*64] bf16
    float* g2 = (float*)R1;                              // [2][N*64] fp32 (after h1 dead)

    float* outF = (float*)d_out;

    const int nodeBlocks = (N + 3) / 4;
    const int nb = (N + 255) / 256;
    const int eb = (E + 255) / 256;

    // weight conversions (tiny)
    cvt_f2b<<<(INDIM * 256 / 4 + 255) / 256, 256, 0, stream>>>(W1, W1b, INDIM * 256 / 4);
    cvt_f2b<<<(256 * HIDD / 4 + 255) / 256, 256, 0, stream>>>(W2, W2b, 256 * HIDD / 4);

    // CSR build
    hipMemsetAsync(cntN, 0, (size_t)2 * N * 4, stream);
    count_dst<<<dim3(eb, 2), 256, 0, stream>>>(ei1v, ei2v, cntN, E, N);
    scan_part<<<dim3(nb, 2), 256, 0, stream>>>(cntN, psum, N);
    scan_tops<<<2, 256, 0, stream>>>(psum, rp, nb, N);
    scan_fin<<<dim3(nb, 2), 256, 0, stream>>>(cntN, psum, rp, N);
    hipMemsetAsync(cntN, 0, (size_t)2 * N * 4, stream);
    fill_csr<<<dim3(eb, 2), 256, 0, stream>>>(ei1v, ei2v, rp, cntN, col, E, N);

    // conv1: h1 = x @ W1 (fp32 A staged in-kernel), alpha fused
    gemm_mfma<128, 64, 64, true><<<dim3(391, 2, 2), 256, 0, stream>>>(
        x1, x2, 0, W1b, h1, (size_t)N * 256, N, INDIM, 256,
        a_src1, a_dst1, as1, ad1, 4, N * 4);
    agg_h4<<<dim3(nodeBlocks, 2), 256, 0, stream>>>(h1, (size_t)N * 256, as1, ad1, N * 4,
                                                    rp, col, b1, g1, (size_t)N * 256, N, E);

    // conv2: h2 = g1 @ W2 (bf16 A), alpha fused
    gemm_mfma<64, 32, 64, false><<<dim3(391, 1, 2), 256, 0, stream>>>(
        g1, nullptr, (size_t)N * 256, W2b, h2, (size_t)N * 64, N, 256, HIDD,
        a_src2, a_dst2, as2, ad2, 1, N);
    agg_h1<<<dim3(nodeBlocks, 2), 256, 0, stream>>>(h2, (size_t)N * 64, as2, ad2,
                                                    rp, col, b2, g2, (size_t)N * 64, N, E);

    // mean pool
    pool_mean<<<dim3(NGR, 2), 256, 0, stream>>>(g2, (size_t)N * 64, ba1, ba2, outF, N);
}